// Round 3
// baseline (387.102 us; speedup 1.0000x reference)
//
#include <hip/hip_runtime.h>
#include <hip/hip_bf16.h>

#define B_ 32
#define T_ 40
#define P_ 256
#define V_ 4096
#define D_ 256
#define DINO_ 384
#define H_ 4
#define L_ 2
#define HD_ 64
#define DFF_ 1024
#define EPS_ 1e-5f

typedef __bf16 bf16;
typedef __bf16 bf16x8 __attribute__((ext_vector_type(8)));
typedef float f32x4 __attribute__((ext_vector_type(4)));

__device__ __forceinline__ float fast_sigmoid(float x) {
  return 1.0f / (1.0f + __expf(-x));
}
// gelu(x) ~= x * sigmoid(1.5957691216*(x + 0.044715 x^3))  (tanh-form)
__device__ __forceinline__ float fast_gelu(float x) {
  float x2 = x * x;
  float w = 1.5957691216057308f * x * fmaf(0.044715f, x2, 1.0f);
  return x * fast_sigmoid(w);
}

__device__ __forceinline__ bf16x8 cvt8(const float* p) {
  float4 f0 = *(const float4*)p;
  float4 f1 = *(const float4*)(p + 4);
  bf16x8 v;
  v[0] = (bf16)f0.x; v[1] = (bf16)f0.y; v[2] = (bf16)f0.z; v[3] = (bf16)f0.w;
  v[4] = (bf16)f1.x; v[5] = (bf16)f1.y; v[6] = (bf16)f1.z; v[7] = (bf16)f1.w;
  return v;
}

// ---------------- embedding: x[b,t,:] = tok_emb[tok] + pos_emb[t] ----------
__global__ void embed_k(const int* __restrict__ tokens, const float* __restrict__ tok_emb,
                        const float* __restrict__ pos_emb, float* __restrict__ x) {
  int m = blockIdx.x;  // b*T + t
  int t = m % T_;
  int d = threadIdx.x;
  int tok = tokens[m];
  x[m * D_ + d] = tok_emb[tok * D_ + d] + pos_emb[t * D_ + d];
}

// ---------------- generic MFMA GEMM: C[m,n] = act(sum_k A[m,k]*W[n*sn+k*sk] + bias[n])
// A fp32. 64x64 block tile, 4 waves (each: 64m x 16n), BK=64.
template <bool WCONTIG>
__global__ __launch_bounds__(256) void gemm_k(
    const float* __restrict__ A, const float* __restrict__ W, const float* __restrict__ bias,
    float* __restrict__ out, int M, int N, int K, int lda, int sn, int sk, int Cm, int Cn,
    long batchA, long batchC, int relu) {
  __shared__ bf16 As[64 * 72];  // pad 64->72: conflict-free b128 frag reads
  __shared__ bf16 Ws[64 * 72];
  const int tid = threadIdx.x;
  const int lane = tid & 63;
  const int wv = tid >> 6;
  const int col = lane & 15;   // input-fragment row (m for A, n for B); output n
  const int quad = lane >> 4;  // k-chunk selector; output row group
  const int bn = blockIdx.x * 64;
  const int bm = blockIdx.y * 64;
  const float* Af = A + blockIdx.z * batchA;
  float* Cp = out + blockIdx.z * batchC;

  f32x4 zero = {0.f, 0.f, 0.f, 0.f};
  f32x4 acc[4];
#pragma unroll
  for (int i = 0; i < 4; ++i) acc[i] = zero;

  for (int kk = 0; kk < K; kk += 64) {
#pragma unroll
    for (int it = 0; it < 2; ++it) {
      int c = tid + it * 256;  // 512 chunks of 8 elems
      int row = c >> 3;
      int kc = (c & 7) * 8;
      *(bf16x8*)&As[row * 72 + kc] = cvt8(Af + (long)(bm + row) * lda + kk + kc);
      bf16x8 wvv;
      if (WCONTIG) {
        wvv = cvt8(W + (long)(bn + row) * sn + kk + kc);
      } else {
#pragma unroll
        for (int j = 0; j < 8; ++j)
          wvv[j] = (bf16)W[(long)(bn + row) * sn + (long)(kk + kc + j) * sk];
      }
      *(bf16x8*)&Ws[row * 72 + kc] = wvv;
    }
    __syncthreads();
#pragma unroll
    for (int ki = 0; ki < 2; ++ki) {
      bf16x8 bfr = *(const bf16x8*)&Ws[(wv * 16 + col) * 72 + ki * 32 + quad * 8];
#pragma unroll
      for (int i = 0; i < 4; ++i) {
        bf16x8 afr = *(const bf16x8*)&As[(i * 16 + col) * 72 + ki * 32 + quad * 8];
        acc[i] = __builtin_amdgcn_mfma_f32_16x16x32_bf16(afr, bfr, acc[i], 0, 0, 0);
      }
    }
    __syncthreads();
  }
  const int n = bn + wv * 16 + col;
  float bv = bias ? bias[n] : 0.0f;
#pragma unroll
  for (int i = 0; i < 4; ++i) {
#pragma unroll
    for (int r = 0; r < 4; ++r) {
      int m = bm + i * 16 + quad * 4 + r;
      float val = acc[i][r] + bv;
      if (relu) val = fmaxf(val, 0.0f);
      Cp[(long)m * Cm + (long)n * Cn] = val;
    }
  }
}

// ---------------- causal attention, one (b,h) per block -------------------
__global__ __launch_bounds__(256) void attn_k(const float* __restrict__ qkv,
                                              float* __restrict__ ctx) {
  __shared__ float q[T_][HD_ + 1];
  __shared__ float k[T_][HD_ + 1];
  __shared__ float v[T_][HD_ + 1];
  __shared__ float s[T_][T_ + 1];
  int h = blockIdx.x, b = blockIdx.y;
  int tid = threadIdx.x;
  for (int idx = tid; idx < T_ * HD_; idx += 256) {
    int t = idx >> 6, d = idx & 63;
    long base = (long)(b * T_ + t) * (3 * D_) + h * HD_ + d;
    q[t][d] = qkv[base];
    k[t][d] = qkv[base + D_];
    v[t][d] = qkv[base + 2 * D_];
  }
  __syncthreads();
  for (int idx = tid; idx < T_ * T_; idx += 256) {
    int i = idx / T_, j = idx - i * T_;
    if (j <= i) {
      float acc = 0.f;
#pragma unroll
      for (int d = 0; d < HD_; ++d) acc += q[i][d] * k[j][d];
      s[i][j] = acc * 0.125f;  // 1/sqrt(64)
    }
  }
  __syncthreads();
  if (tid < T_) {
    int i = tid;
    float mx = -1e30f;
    for (int j = 0; j <= i; ++j) mx = fmaxf(mx, s[i][j]);
    float sum = 0.f;
    for (int j = 0; j <= i; ++j) {
      float e = __expf(s[i][j] - mx);
      s[i][j] = e;
      sum += e;
    }
    float inv = 1.0f / sum;
    for (int j = 0; j <= i; ++j) s[i][j] *= inv;
  }
  __syncthreads();
  for (int idx = tid; idx < T_ * HD_; idx += 256) {
    int i = idx >> 6, d = idx & 63;
    float acc = 0.f;
    for (int j = 0; j <= i; ++j) acc += s[i][j] * v[j][d];
    ctx[(long)(b * T_ + i) * D_ + h * HD_ + d] = acc;
  }
}

// ---------------- residual + LayerNorm, one (b,t) per block ---------------
__global__ __launch_bounds__(256) void ln_k(float* __restrict__ x, const float* __restrict__ y,
                                            const float* __restrict__ g,
                                            const float* __restrict__ be) {
  __shared__ float red[4];
  int m = blockIdx.x, d = threadIdx.x;
  int lane = d & 63, wv = d >> 6;
  float val = x[m * D_ + d] + y[m * D_ + d];
  float sv = val;
#pragma unroll
  for (int mk = 1; mk < 64; mk <<= 1) sv += __shfl_xor(sv, mk);
  if (lane == 0) red[wv] = sv;
  __syncthreads();
  float mean = (red[0] + red[1] + red[2] + red[3]) * (1.0f / D_);
  __syncthreads();
  float c = val - mean;
  float s2 = c * c;
#pragma unroll
  for (int mk = 1; mk < 64; mk <<= 1) s2 += __shfl_xor(s2, mk);
  if (lane == 0) red[wv] = s2;
  __syncthreads();
  float var = (red[0] + red[1] + red[2] + red[3]) * (1.0f / D_);
  x[m * D_ + d] = c * rsqrtf(var + EPS_) * g[d] + be[d];
}

// ---------------- ctx shift: ctx[b,t] = t==0 ? 0 : enc[b,t-1] -------------
__global__ void shift_k(const float* __restrict__ x, float* __restrict__ ctx) {
  int m = blockIdx.x, d = threadIdx.x;
  int t = m % T_;
  ctx[m * D_ + d] = (t == 0) ? 0.0f : x[(m - 1) * D_ + d];
}

// ---------------- gather cls_w rows + beff = wsel.fus_b2 + cls_b ----------
__global__ __launch_bounds__(256) void gather_k(
    const int* __restrict__ tokens, const float* __restrict__ cls_w,
    const float* __restrict__ cls_b, const float* __restrict__ fus_b2,
    float* __restrict__ wsel, float* __restrict__ beff) {
  __shared__ float red[4];
  int m = blockIdx.x, d = threadIdx.x;
  int lane = d & 63, wv = d >> 6;
  int tok = tokens[m];
  float wval = cls_w[tok * D_ + d];
  wsel[m * D_ + d] = wval;
  float pv = wval * fus_b2[d];
#pragma unroll
  for (int mk = 1; mk < 64; mk <<= 1) pv += __shfl_xor(pv, mk);
  if (lane == 0) red[wv] = pv;
  __syncthreads();
  if (d == 0) beff[m] = red[0] + red[1] + red[2] + red[3] + cls_b[tok];
}

// ---------------- final: out[b,p,t] = sigmoid(sum_e gelu(pp+cp)*we + beff) -
__global__ __launch_bounds__(256) void final_k(const float* __restrict__ pprojT,
                                               const float* __restrict__ cw,
                                               const float* __restrict__ beff,
                                               float* __restrict__ out) {
  int lane = threadIdx.x & 63, wv = threadIdx.x >> 6;
  int p = blockIdx.x * 64 + lane;
  int t0 = blockIdx.y * 8 + wv * 2;
  int b = blockIdx.z;
  const float* ppb = pprojT + (long)b * (D_ * P_);  // [e][p]
  const float* cw0 = cw + (long)(b * T_ + t0) * (D_ * 2);
  const float* cw1 = cw0 + D_ * 2;
  float acc0 = 0.f, acc1 = 0.f;
#pragma unroll 4
  for (int e = 0; e < D_; ++e) {
    float pp = ppb[e * P_ + p];
    float2 c0 = *(const float2*)&cw0[e * 2];
    float2 c1 = *(const float2*)&cw1[e * 2];
    acc0 += fast_gelu(pp + c0.x) * c0.y;
    acc1 += fast_gelu(pp + c1.x) * c1.y;
  }
  int m = b * T_ + t0;
  float l0 = acc0 + beff[m];
  float l1 = acc1 + beff[m + 1];
  long ob = (long)(b * P_ + p) * T_ + t0;
  out[ob] = fast_sigmoid(l0);
  out[ob + 1] = fast_sigmoid(l1);
}

extern "C" void kernel_launch(void* const* d_in, const int* in_sizes, int n_in, void* d_out,
                              int out_size, void* d_ws, size_t ws_size, hipStream_t stream) {
  const float* patches = (const float*)d_in[0];
  const int* tokens = (const int*)d_in[1];
  const float* tok_emb = (const float*)d_in[2];
  const float* pos_emb = (const float*)d_in[3];
  const float* qkv_w = (const float*)d_in[4];
  const float* qkv_b = (const float*)d_in[5];
  const float* out_w = (const float*)d_in[6];
  const float* out_b = (const float*)d_in[7];
  const float* ln1_s = (const float*)d_in[8];
  const float* ln1_b = (const float*)d_in[9];
  const float* w1 = (const float*)d_in[10];
  const float* b1 = (const float*)d_in[11];
  const float* w2 = (const float*)d_in[12];
  const float* b2 = (const float*)d_in[13];
  const float* ln2_s = (const float*)d_in[14];
  const float* ln2_b = (const float*)d_in[15];
  const float* fus_w1 = (const float*)d_in[16];
  const float* fus_b1 = (const float*)d_in[17];
  const float* fus_w2 = (const float*)d_in[18];
  const float* fus_b2 = (const float*)d_in[19];
  const float* cls_w = (const float*)d_in[20];
  const float* cls_b = (const float*)d_in[21];
  float* out = (float*)d_out;

  float* xbuf = (float*)d_ws;                    // 1280*256
  float* qkvbuf = xbuf + B_ * T_ * D_;           // 1280*768
  float* tmp = qkvbuf + B_ * T_ * 3 * D_;        // 1280*256
  float* hbuf = tmp + B_ * T_ * D_;              // 1280*1024
  float* ctxbuf = hbuf + B_ * T_ * DFF_;         // 1280*256
  float* pprojT = ctxbuf + B_ * T_ * D_;         // 32*256*256 [b][e][p]
  float* cwbuf = pprojT + (long)B_ * D_ * P_;    // 1280*256*2 interleaved {cproj,weff}
  float* wselbuf = cwbuf + B_ * T_ * D_ * 2;     // 1280*256
  float* beff = wselbuf + B_ * T_ * D_;          // 1280

  const int MT = B_ * T_;  // 1280

  embed_k<<<MT, D_, 0, stream>>>(tokens, tok_emb, pos_emb, xbuf);

  for (int l = 0; l < L_; ++l) {
    // qkv = x @ qkv_w^T + qkv_b
    gemm_k<true><<<dim3(12, 20, 1), 256, 0, stream>>>(
        xbuf, qkv_w + (long)l * 3 * D_ * D_, qkv_b + l * 3 * D_, qkvbuf, MT, 3 * D_, D_, D_,
        D_, 1, 3 * D_, 1, 0, 0, 0);
    attn_k<<<dim3(H_, B_), 256, 0, stream>>>(qkvbuf, hbuf);
    // proj = ctx @ out_w^T + out_b
    gemm_k<true><<<dim3(4, 20, 1), 256, 0, stream>>>(
        hbuf, out_w + (long)l * D_ * D_, out_b + l * D_, tmp, MT, D_, D_, D_, D_, 1, D_, 1,
        0, 0, 0);
    ln_k<<<MT, D_, 0, stream>>>(xbuf, tmp, ln1_s + l * D_, ln1_b + l * D_);
    // h = relu(x @ w1^T + b1)
    gemm_k<true><<<dim3(16, 20, 1), 256, 0, stream>>>(
        xbuf, w1 + (long)l * DFF_ * D_, b1 + l * DFF_, hbuf, MT, DFF_, D_, D_, D_, 1, DFF_,
        1, 0, 0, 1);
    // y = h @ w2^T + b2
    gemm_k<true><<<dim3(4, 20, 1), 256, 0, stream>>>(
        hbuf, w2 + (long)l * D_ * DFF_, b2 + l * D_, tmp, MT, D_, DFF_, DFF_, DFF_, 1, D_, 1,
        0, 0, 0);
    ln_k<<<MT, D_, 0, stream>>>(xbuf, tmp, ln2_s + l * D_, ln2_b + l * D_);
  }

  shift_k<<<MT, D_, 0, stream>>>(xbuf, ctxbuf);
  // pproj[b][e][p] = (patches @ wp^T)^T  (batched over b, transposed out)
  gemm_k<true><<<dim3(4, 4, B_), 256, 0, stream>>>(
      patches, fus_w1, nullptr, pprojT, P_, D_, DINO_, DINO_, DINO_ + D_, 1, 1, P_,
      (long)P_ * DINO_, (long)D_ * P_, 0);
  // cproj (even slots of cw)
  gemm_k<true><<<dim3(4, 20, 1), 256, 0, stream>>>(
      ctxbuf, fus_w1 + DINO_, fus_b1, cwbuf, MT, D_, D_, D_, DINO_ + D_, 1, 2 * D_, 2, 0, 0,
      0);
  gather_k<<<MT, D_, 0, stream>>>(tokens, cls_w, cls_b, fus_b2, wselbuf, beff);
  // weff = wsel @ fus_w2 (odd slots of cw); W[n,k]=fus_w2[k*D+n] -> sn=1, sk=D
  gemm_k<false><<<dim3(4, 20, 1), 256, 0, stream>>>(
      wselbuf, fus_w2, nullptr, cwbuf + 1, MT, D_, D_, D_, 1, D_, 2 * D_, 2, 0, 0, 0);

  final_k<<<dim3(4, 5, 32), 256, 0, stream>>>(pprojT, cwbuf, beff, out);
}

// Round 4
// 317.581 us; speedup vs baseline: 1.2189x; 1.2189x over previous
//
#include <hip/hip_runtime.h>
#include <hip/hip_bf16.h>

#define B_ 32
#define T_ 40
#define P_ 256
#define V_ 4096
#define D_ 256
#define DINO_ 384
#define H_ 4
#define L_ 2
#define HD_ 64
#define DFF_ 1024
#define EPS_ 1e-5f

typedef __bf16 bf16;
typedef __bf16 bf16x8 __attribute__((ext_vector_type(8)));
typedef float f32x4 __attribute__((ext_vector_type(4)));

__device__ __forceinline__ float fast_sigmoid(float x) {
  return 1.0f / (1.0f + __expf(-x));
}
// gelu(x) ~= x * sigmoid(1.5957691216*(x + 0.044715 x^3))  (tanh-form)
__device__ __forceinline__ float fast_gelu(float x) {
  float x2 = x * x;
  float w = 1.5957691216057308f * x * fmaf(0.044715f, x2, 1.0f);
  return x * fast_sigmoid(w);
}

__device__ __forceinline__ bf16x8 cvt8(const float* p) {
  float4 f0 = *(const float4*)p;
  float4 f1 = *(const float4*)(p + 4);
  bf16x8 v;
  v[0] = (bf16)f0.x; v[1] = (bf16)f0.y; v[2] = (bf16)f0.z; v[3] = (bf16)f0.w;
  v[4] = (bf16)f1.x; v[5] = (bf16)f1.y; v[6] = (bf16)f1.z; v[7] = (bf16)f1.w;
  return v;
}

// ---------------- embedding: x[b,t,:] = tok_emb[tok] + pos_emb[t] ----------
__global__ void embed_k(const int* __restrict__ tokens, const float* __restrict__ tok_emb,
                        const float* __restrict__ pos_emb, float* __restrict__ x) {
  int m = blockIdx.x;  // b*T + t
  int t = m % T_;
  int d = threadIdx.x;
  int tok = tokens[m];
  x[m * D_ + d] = tok_emb[tok * D_ + d] + pos_emb[t * D_ + d];
}

// ---------------- MFMA GEMM, 32x32 tile/block, 4 waves (each one 16x16) ----
// C[m,n] = act(sum_k A[m,k] * W[n,k] + bias[n]); A,W fp32 row-major (lda/ldw),
// K multiple of 64. Grid: (N/32, M/32, batch).
__global__ __launch_bounds__(256) void gemm32_k(
    const float* __restrict__ A, const float* __restrict__ W, const float* __restrict__ bias,
    float* __restrict__ out, int K, int lda, int ldw, int Cm, int Cn,
    long batchA, long batchC, int relu) {
  __shared__ bf16 As[32 * 72];  // pad 64->72 bf16: conflict-free b128 frag reads
  __shared__ bf16 Ws[32 * 72];
  const int tid = threadIdx.x;
  const int lane = tid & 63;
  const int wv = tid >> 6;
  const int mi = wv & 1, ni = wv >> 1;
  const int col = lane & 15;   // fragment row (m for A, n for B); output n
  const int quad = lane >> 4;  // k-chunk selector; output row group
  const int bn = blockIdx.x * 32;
  const int bm = blockIdx.y * 32;
  const float* Af = A + blockIdx.z * batchA;
  float* Cp = out + blockIdx.z * batchC;

  f32x4 acc = {0.f, 0.f, 0.f, 0.f};

  const int row = tid >> 3;        // 0..31
  const int kc = (tid & 7) * 8;    // 0..56
  for (int kk = 0; kk < K; kk += 64) {
    *(bf16x8*)&As[row * 72 + kc] = cvt8(Af + (long)(bm + row) * lda + kk + kc);
    *(bf16x8*)&Ws[row * 72 + kc] = cvt8(W + (long)(bn + row) * ldw + kk + kc);
    __syncthreads();
#pragma unroll
    for (int ki = 0; ki < 2; ++ki) {
      bf16x8 afr = *(const bf16x8*)&As[(mi * 16 + col) * 72 + ki * 32 + quad * 8];
      bf16x8 bfr = *(const bf16x8*)&Ws[(ni * 16 + col) * 72 + ki * 32 + quad * 8];
      acc = __builtin_amdgcn_mfma_f32_16x16x32_bf16(afr, bfr, acc, 0, 0, 0);
    }
    __syncthreads();
  }
  const int n = bn + ni * 16 + col;
  float bv = bias ? bias[n] : 0.0f;
#pragma unroll
  for (int r = 0; r < 4; ++r) {
    int m = bm + mi * 16 + quad * 4 + r;
    float val = acc[r] + bv;
    if (relu) val = fmaxf(val, 0.0f);
    Cp[(long)m * Cm + (long)n * Cn] = val;
  }
}

// ---------------- 256x256 fp32 transpose (for fus_w2) ----------------------
__global__ __launch_bounds__(256) void transpose_k(const float* __restrict__ in,
                                                   float* __restrict__ out) {
  __shared__ float tile[32][33];
  int bx = blockIdx.x * 32, by = blockIdx.y * 32;
  int tx = threadIdx.x & 31, ty = threadIdx.x >> 5;  // 32 x 8
#pragma unroll
  for (int i = 0; i < 32; i += 8) tile[ty + i][tx] = in[(by + ty + i) * D_ + bx + tx];
  __syncthreads();
#pragma unroll
  for (int i = 0; i < 32; i += 8) out[(bx + ty + i) * D_ + by + tx] = tile[tx][ty + i];
}

// ---------------- causal attention, one (b,h) per block -------------------
__global__ __launch_bounds__(256) void attn_k(const float* __restrict__ qkv,
                                              float* __restrict__ ctx) {
  __shared__ float q[T_][HD_ + 1];
  __shared__ float k[T_][HD_ + 1];
  __shared__ float v[T_][HD_ + 1];
  __shared__ float s[T_][T_ + 1];
  int h = blockIdx.x, b = blockIdx.y;
  int tid = threadIdx.x;
  for (int idx = tid; idx < T_ * HD_; idx += 256) {
    int t = idx >> 6, d = idx & 63;
    long base = (long)(b * T_ + t) * (3 * D_) + h * HD_ + d;
    q[t][d] = qkv[base];
    k[t][d] = qkv[base + D_];
    v[t][d] = qkv[base + 2 * D_];
  }
  __syncthreads();
  for (int idx = tid; idx < T_ * T_; idx += 256) {
    int i = idx / T_, j = idx - i * T_;
    if (j <= i) {
      float acc = 0.f;
#pragma unroll
      for (int d = 0; d < HD_; ++d) acc += q[i][d] * k[j][d];
      s[i][j] = acc * 0.125f;  // 1/sqrt(64)
    }
  }
  __syncthreads();
  if (tid < T_) {
    int i = tid;
    float mx = -1e30f;
    for (int j = 0; j <= i; ++j) mx = fmaxf(mx, s[i][j]);
    float sum = 0.f;
    for (int j = 0; j <= i; ++j) {
      float e = __expf(s[i][j] - mx);
      s[i][j] = e;
      sum += e;
    }
    float inv = 1.0f / sum;
    for (int j = 0; j <= i; ++j) s[i][j] *= inv;
  }
  __syncthreads();
  for (int idx = tid; idx < T_ * HD_; idx += 256) {
    int i = idx >> 6, d = idx & 63;
    float acc = 0.f;
    for (int j = 0; j <= i; ++j) acc += s[i][j] * v[j][d];
    ctx[(long)(b * T_ + i) * D_ + h * HD_ + d] = acc;
  }
}

// ---------------- residual + LayerNorm, one (b,t) per block ---------------
__global__ __launch_bounds__(256) void ln_k(float* __restrict__ x, const float* __restrict__ y,
                                            const float* __restrict__ g,
                                            const float* __restrict__ be) {
  __shared__ float red[4];
  int m = blockIdx.x, d = threadIdx.x;
  int lane = d & 63, wv = d >> 6;
  float val = x[m * D_ + d] + y[m * D_ + d];
  float sv = val;
#pragma unroll
  for (int mk = 1; mk < 64; mk <<= 1) sv += __shfl_xor(sv, mk);
  if (lane == 0) red[wv] = sv;
  __syncthreads();
  float mean = (red[0] + red[1] + red[2] + red[3]) * (1.0f / D_);
  __syncthreads();
  float c = val - mean;
  float s2 = c * c;
#pragma unroll
  for (int mk = 1; mk < 64; mk <<= 1) s2 += __shfl_xor(s2, mk);
  if (lane == 0) red[wv] = s2;
  __syncthreads();
  float var = (red[0] + red[1] + red[2] + red[3]) * (1.0f / D_);
  x[m * D_ + d] = c * rsqrtf(var + EPS_) * g[d] + be[d];
}

// ---------------- ctx shift: ctx[b,t] = t==0 ? 0 : enc[b,t-1] -------------
__global__ void shift_k(const float* __restrict__ x, float* __restrict__ ctx) {
  int m = blockIdx.x, d = threadIdx.x;
  int t = m % T_;
  ctx[m * D_ + d] = (t == 0) ? 0.0f : x[(m - 1) * D_ + d];
}

// ---------------- gather cls_w rows + beff = wsel.fus_b2 + cls_b ----------
__global__ __launch_bounds__(256) void gather_k(
    const int* __restrict__ tokens, const float* __restrict__ cls_w,
    const float* __restrict__ cls_b, const float* __restrict__ fus_b2,
    float* __restrict__ wsel, float* __restrict__ beff) {
  __shared__ float red[4];
  int m = blockIdx.x, d = threadIdx.x;
  int lane = d & 63, wv = d >> 6;
  int tok = tokens[m];
  float wval = cls_w[tok * D_ + d];
  wsel[m * D_ + d] = wval;
  float pv = wval * fus_b2[d];
#pragma unroll
  for (int mk = 1; mk < 64; mk <<= 1) pv += __shfl_xor(pv, mk);
  if (lane == 0) red[wv] = pv;
  __syncthreads();
  if (d == 0) beff[m] = red[0] + red[1] + red[2] + red[3] + cls_b[tok];
}

// ---------------- final: out[b,p,t] = sigmoid(sum_e gelu(pp+cp)*we + beff) -
// grid (P/64, T/4, B); each wave owns one t, lanes own p.
__global__ __launch_bounds__(256) void final_k(const float* __restrict__ pprojT,
                                               const float* __restrict__ cw,
                                               const float* __restrict__ beff,
                                               float* __restrict__ out) {
  int lane = threadIdx.x & 63, wv = threadIdx.x >> 6;
  int p = blockIdx.x * 64 + lane;
  int t = blockIdx.y * 4 + wv;
  int b = blockIdx.z;
  const float* ppb = pprojT + (long)b * (D_ * P_);         // [e][p]
  const float* cwt = cw + (long)(b * T_ + t) * (D_ * 2);   // {cproj, weff} pairs
  float acc = 0.f;
#pragma unroll 4
  for (int e = 0; e < D_; ++e) {
    float pp = ppb[e * P_ + p];
    float2 c = *(const float2*)&cwt[e * 2];
    acc += fast_gelu(pp + c.x) * c.y;
  }
  int m = b * T_ + t;
  out[(long)(b * P_ + p) * T_ + t] = fast_sigmoid(acc + beff[m]);
}

extern "C" void kernel_launch(void* const* d_in, const int* in_sizes, int n_in, void* d_out,
                              int out_size, void* d_ws, size_t ws_size, hipStream_t stream) {
  const float* patches = (const float*)d_in[0];
  const int* tokens = (const int*)d_in[1];
  const float* tok_emb = (const float*)d_in[2];
  const float* pos_emb = (const float*)d_in[3];
  const float* qkv_w = (const float*)d_in[4];
  const float* qkv_b = (const float*)d_in[5];
  const float* out_w = (const float*)d_in[6];
  const float* out_b = (const float*)d_in[7];
  const float* ln1_s = (const float*)d_in[8];
  const float* ln1_b = (const float*)d_in[9];
  const float* w1 = (const float*)d_in[10];
  const float* b1 = (const float*)d_in[11];
  const float* w2 = (const float*)d_in[12];
  const float* b2 = (const float*)d_in[13];
  const float* ln2_s = (const float*)d_in[14];
  const float* ln2_b = (const float*)d_in[15];
  const float* fus_w1 = (const float*)d_in[16];
  const float* fus_b1 = (const float*)d_in[17];
  const float* fus_w2 = (const float*)d_in[18];
  const float* fus_b2 = (const float*)d_in[19];
  const float* cls_w = (const float*)d_in[20];
  const float* cls_b = (const float*)d_in[21];
  float* out = (float*)d_out;

  float* xbuf = (float*)d_ws;                    // 1280*256
  float* qkvbuf = xbuf + B_ * T_ * D_;           // 1280*768
  float* tmp = qkvbuf + B_ * T_ * 3 * D_;        // 1280*256
  float* hbuf = tmp + B_ * T_ * D_;              // 1280*1024
  float* ctxbuf = hbuf + B_ * T_ * DFF_;         // 1280*256
  float* pprojT = ctxbuf + B_ * T_ * D_;         // 32*256*256 [b][e][p]
  float* cwbuf = pprojT + (long)B_ * D_ * P_;    // 1280*256*2 interleaved {cproj,weff}
  float* wselbuf = cwbuf + B_ * T_ * D_ * 2;     // 1280*256
  float* beff = wselbuf + B_ * T_ * D_;          // 1280
  float* w2T = beff + B_ * T_;                   // 256*256 (fus_w2 transposed)

  const int MT = B_ * T_;  // 1280

  embed_k<<<MT, D_, 0, stream>>>(tokens, tok_emb, pos_emb, xbuf);

  for (int l = 0; l < L_; ++l) {
    // qkv = x @ qkv_w^T + qkv_b
    gemm32_k<<<dim3(24, 40, 1), 256, 0, stream>>>(
        xbuf, qkv_w + (long)l * 3 * D_ * D_, qkv_b + l * 3 * D_, qkvbuf, D_, D_, D_,
        3 * D_, 1, 0, 0, 0);
    attn_k<<<dim3(H_, B_), 256, 0, stream>>>(qkvbuf, hbuf);
    // proj = ctx @ out_w^T + out_b
    gemm32_k<<<dim3(8, 40, 1), 256, 0, stream>>>(
        hbuf, out_w + (long)l * D_ * D_, out_b + l * D_, tmp, D_, D_, D_, D_, 1, 0, 0, 0);
    ln_k<<<MT, D_, 0, stream>>>(xbuf, tmp, ln1_s + l * D_, ln1_b + l * D_);
    // h = relu(x @ w1^T + b1)
    gemm32_k<<<dim3(32, 40, 1), 256, 0, stream>>>(
        xbuf, w1 + (long)l * DFF_ * D_, b1 + l * DFF_, hbuf, D_, D_, D_, DFF_, 1, 0, 0, 1);
    // y = h @ w2^T + b2
    gemm32_k<<<dim3(8, 40, 1), 256, 0, stream>>>(
        hbuf, w2 + (long)l * D_ * DFF_, b2 + l * D_, tmp, DFF_, DFF_, DFF_, D_, 1, 0, 0, 0);
    ln_k<<<MT, D_, 0, stream>>>(xbuf, tmp, ln2_s + l * D_, ln2_b + l * D_);
  }

  shift_k<<<MT, D_, 0, stream>>>(xbuf, ctxbuf);
  transpose_k<<<dim3(8, 8), 256, 0, stream>>>(fus_w2, w2T);
  // pproj[b][e][p] = (patches @ wp^T)^T  (batched over b, transposed out)
  gemm32_k<<<dim3(8, 8, B_), 256, 0, stream>>>(
      patches, fus_w1, nullptr, pprojT, DINO_, DINO_, DINO_ + D_, 1, P_,
      (long)P_ * DINO_, (long)D_ * P_, 0);
  // cproj (even slots of cw)
  gemm32_k<<<dim3(8, 40, 1), 256, 0, stream>>>(
      ctxbuf, fus_w1 + DINO_, fus_b1, cwbuf, D_, D_, DINO_ + D_, 2 * D_, 2, 0, 0, 0);
  gather_k<<<MT, D_, 0, stream>>>(tokens, cls_w, cls_b, fus_b2, wselbuf, beff);
  // weff = wsel @ fus_w2 (odd slots of cw), via transposed w2T (contiguous k)
  gemm32_k<<<dim3(8, 40, 1), 256, 0, stream>>>(
      wselbuf, w2T, nullptr, cwbuf + 1, D_, D_, D_, 2 * D_, 2, 0, 0, 0);

  final_k<<<dim3(4, 10, 32), 256, 0, stream>>>(pprojT, cwbuf, beff, out);
}